// Round 1
// baseline (3033.705 us; speedup 1.0000x reference)
//
#include <hip/hip_runtime.h>
#include <hip/hip_bf16.h>

// Problem dims
#define B_   512
#define WIN_ 128
#define D_   256
#define H_   512
#define O_   64
#define P_   64
#define K2H  1024   // 2H (q = [h|c])
#define KG   832    // gates GEMM K = O(64) + D(256) + H(512)
#define NQY  320    // fused Wq(256) + y(64) GEMM N

typedef __attribute__((ext_vector_type(8))) short bf16x8;
typedef __attribute__((ext_vector_type(4))) float f32x4;
using bf16 = __hip_bfloat16;

__device__ __forceinline__ float fast_tanh(float x){
    float e = __expf(2.f * x);
    return 1.f - __fdividef(2.f, e + 1.f);
}
__device__ __forceinline__ float fast_sig(float x){
    return __fdividef(1.f, 1.f + __expf(-x));
}

// ---------------- prep: dtype conversions + weight packing ----------------
__global__ void k_prep(const float* __restrict__ x, const float* __restrict__ W,
                       const float* __restrict__ U, const float* __restrict__ W_ih,
                       const float* __restrict__ W_hh, const float* __restrict__ b_ih,
                       const float* __restrict__ b_hh, const float* __restrict__ Wd,
                       bf16* __restrict__ x_bf, bf16* __restrict__ Wcomb,
                       bf16* __restrict__ Wqy, bf16* __restrict__ U_bf,
                       float* __restrict__ bsum, bf16* __restrict__ A0)
{
    const long NX  = (long)B_ * WIN_ * D_;        // 16,777,216
    const long NWC = (long)2048 * KG;             // 1,703,936
    const long NWQ = (long)NQY * K2H;             // 327,680
    const long NU  = (long)D_ * D_;               // 65,536
    const long NB  = 2048;
    const long NAY = (long)B_ * O_;               // zero y-slot of A0
    const long total = NX + NWC + NWQ + NU + NB + NAY;
    for (long i = (long)blockIdx.x * blockDim.x + threadIdx.x; i < total;
         i += (long)gridDim.x * blockDim.x) {
        long j = i;
        if (j < NX) { x_bf[j] = __float2bfloat16(x[j]); continue; }
        j -= NX;
        if (j < NWC) {
            long n = j / KG, k = j % KG;
            float v = (k < 320) ? W_ih[n * 320 + k] : W_hh[n * 512 + (k - 320)];
            Wcomb[j] = __float2bfloat16(v); continue;
        }
        j -= NWC;
        if (j < NWQ) {
            long n = j / K2H, k = j % K2H;
            float v;
            if (n < 256) v = W[n * K2H + k];
            else { long o = n - 256; v = (k < 512) ? Wd[o * 512 + k] : 0.f; }
            Wqy[j] = __float2bfloat16(v); continue;
        }
        j -= NWQ;
        if (j < NU) { U_bf[j] = __float2bfloat16(U[j]); continue; }
        j -= NU;
        if (j < NB) { bsum[j] = b_ih[j] + b_hh[j]; continue; }
        j -= NB;
        { long b = j / O_, o = j % O_; A0[b * KG + o] = __float2bfloat16(0.f); }
    }
}

// ---------------- init: h0 = tanh(x_last@Ws^T+bs), c0 = sig(x_last@Wc^T+bc) ----
__global__ void __launch_bounds__(256) k_init(const float* __restrict__ x,
                       const float* __restrict__ Ws, const float* __restrict__ bs,
                       const float* __restrict__ Wc, const float* __restrict__ bc,
                       bf16* __restrict__ q_buf, bf16* __restrict__ A0,
                       float* __restrict__ c_f32)
{
    __shared__ __align__(16) float xl[D_];
    int b = blockIdx.x >> 1;
    int j = (blockIdx.x & 1) * 256 + threadIdx.x;  // j in [0,512)
    xl[threadIdx.x] = x[(long)b * (WIN_ * D_) + 127 * D_ + threadIdx.x];
    __syncthreads();
    float hv = bs[j], cv = bc[j];
    const float* wsr = Ws + (long)j * D_;
    const float* wcr = Wc + (long)j * D_;
    #pragma unroll 4
    for (int k = 0; k < D_; k += 4) {
        float4 xa = *(const float4*)&xl[k];
        float4 wa = *(const float4*)&wsr[k];
        float4 wb = *(const float4*)&wcr[k];
        hv += xa.x*wa.x + xa.y*wa.y + xa.z*wa.z + xa.w*wa.w;
        cv += xa.x*wb.x + xa.y*wb.y + xa.z*wb.z + xa.w*wb.w;
    }
    hv = fast_tanh(hv); cv = fast_sig(cv);
    bf16 hb = __float2bfloat16(hv);
    q_buf[(long)b * K2H + j]       = hb;
    q_buf[(long)b * K2H + 512 + j] = __float2bfloat16(cv);
    A0[(long)b * KG + 320 + j]     = hb;
    c_f32[(long)b * H_ + j]        = cv;
}

// ---------------- Uk[b] = U @ x[b]^T  (per batch, MFMA TN) ----------------
// Uk layout: [b][v(256)][w(128)], bf16
__global__ void __launch_bounds__(256) k_uk(const bf16* __restrict__ U_bf,
                    const bf16* __restrict__ x_bf, bf16* __restrict__ Uk)
{
    int b  = blockIdx.x;
    int v0 = (blockIdx.y >> 1) * 64;
    int w0 = (blockIdx.y & 1) * 64;
    int lane = threadIdx.x & 63;
    int wave = threadIdx.x >> 6;
    int r  = lane & 15;
    int ko = (lane >> 4) * 8;
    const short* Up = (const short*)U_bf;
    const short* xp = (const short*)x_bf + (long)b * (WIN_ * D_);
    f32x4 acc[4] = {};
    int vrow = v0 + wave * 16 + r;
    for (int k0 = 0; k0 < D_; k0 += 32) {
        bf16x8 a = *(const bf16x8*)(Up + (long)vrow * D_ + k0 + ko);
        #pragma unroll
        for (int f = 0; f < 4; ++f) {
            bf16x8 bb = *(const bf16x8*)(xp + (long)(w0 + f*16 + r) * D_ + k0 + ko);
            acc[f] = __builtin_amdgcn_mfma_f32_16x16x32_bf16(a, bb, acc[f], 0, 0, 0);
        }
    }
    bf16* up = Uk + (long)b * (D_ * WIN_);
    int vbase = v0 + wave * 16 + (lane >> 4) * 4;
    #pragma unroll
    for (int f = 0; f < 4; ++f) {
        int w = w0 + f * 16 + r;
        #pragma unroll
        for (int j = 0; j < 4; ++j)
            up[(long)(vbase + j) * WIN_ + w] = __float2bfloat16(acc[f][j]);
    }
}

// ---------------- fused Wq + y GEMM: [h|c](512x1024) @ Wqy^T(320x1024) -------
// n<256 -> Wq ; n>=256 -> y (bias bd), written to d_out step ystep + A_buf
__global__ void __launch_bounds__(64) k_wqy(const bf16* __restrict__ q_buf,
                     const bf16* __restrict__ Wqy, const float* __restrict__ bd,
                     float* __restrict__ Wq, float* __restrict__ out_y,
                     bf16* __restrict__ A_buf, int ystep)
{
    int m0 = blockIdx.x * 16;
    int n0 = blockIdx.y * 32;
    int lane = threadIdx.x & 63;
    int r  = lane & 15;
    int ko = (lane >> 4) * 8;
    const short* qp = (const short*)q_buf;
    const short* wp = (const short*)Wqy;
    f32x4 acc[2] = {};
    for (int k0 = 0; k0 < K2H; k0 += 32) {
        bf16x8 a = *(const bf16x8*)(qp + (long)(m0 + r) * K2H + k0 + ko);
        #pragma unroll
        for (int f = 0; f < 2; ++f) {
            bf16x8 bb = *(const bf16x8*)(wp + (long)(n0 + f*16 + r) * K2H + k0 + ko);
            acc[f] = __builtin_amdgcn_mfma_f32_16x16x32_bf16(a, bb, acc[f], 0, 0, 0);
        }
    }
    #pragma unroll
    for (int f = 0; f < 2; ++f) {
        int n = n0 + f * 16 + r;
        #pragma unroll
        for (int j = 0; j < 4; ++j) {
            int b = m0 + (lane >> 4) * 4 + j;
            float val = acc[f][j];
            if (n < 256) {
                Wq[(long)b * D_ + n] = val;
            } else if (ystep >= 0) {
                int o = n - 256;
                val += bd[o];
                out_y[((long)b * P_ + ystep) * O_ + o] = val;
                A_buf[(long)b * KG + o] = __float2bfloat16(val);
            }
        }
    }
}

// ---------------- attention: score -> softmax -> ctx  (one block per batch) --
__global__ void __launch_bounds__(256) k_att(const float* __restrict__ Wq,
                     const float* __restrict__ V, const bf16* __restrict__ Uk,
                     const bf16* __restrict__ x_bf, float* __restrict__ out_w,
                     bf16* __restrict__ A_buf, int s)
{
    __shared__ float wq_s[D_];
    __shared__ float v_s[D_];
    __shared__ float part[256];
    __shared__ float red[128];
    __shared__ float att_s[WIN_];
    int b = blockIdx.x;
    int t = threadIdx.x;
    wq_s[t] = Wq[(long)b * D_ + t];
    v_s[t]  = V[t];
    __syncthreads();

    int w  = t & 127;
    int vh = t >> 7;   // v-half: 0 or 1
    const bf16* ukp = Uk + (long)b * (D_ * WIN_) + (long)vh * 128 * WIN_ + w;
    float sc = 0.f;
    #pragma unroll 8
    for (int i = 0; i < 128; ++i) {
        int v = vh * 128 + i;
        float uk = __bfloat162float(ukp[(long)i * WIN_]);
        sc += v_s[v] * fast_tanh(wq_s[v] + uk);
    }
    part[t] = sc;
    __syncthreads();
    float sw = 0.f;
    if (t < 128) { sw = part[t] + part[t + 128]; red[t] = sw; }
    __syncthreads();
    for (int off = 64; off > 0; off >>= 1) {
        if (t < off) red[t] = fmaxf(red[t], red[t + off]);
        __syncthreads();
    }
    float m = red[0];
    __syncthreads();
    float ew = 0.f;
    if (t < 128) { ew = __expf(sw - m); red[t] = ew; }
    __syncthreads();
    for (int off = 64; off > 0; off >>= 1) {
        if (t < off) red[t] += red[t + off];
        __syncthreads();
    }
    float inv = __fdividef(1.f, red[0]);
    if (t < 128) {
        float a = ew * inv;
        att_s[t] = a;
        out_w[((long)b * P_ + s) * WIN_ + t] = a;
    }
    __syncthreads();

    // ctx[d] = sum_w att[w] * x[b][w][d]
    int d = t;
    const bf16* xbp = x_bf + (long)b * (WIN_ * D_) + d;
    float ctx = 0.f;
    #pragma unroll 8
    for (int wi = 0; wi < WIN_; ++wi)
        ctx += att_s[wi] * __bfloat162float(xbp[(long)wi * D_]);
    A_buf[(long)b * KG + 64 + d] = __float2bfloat16(ctx);
}

// ---------------- gates GEMM + LSTM pointwise epilogue -----------------------
// A_in = [y|ctx|h] (512 x 832) bf16 ; Wcomb = [W_ih|W_hh] (2048 x 832) bf16
// wave computes 16 batches x 16 gate-dims, all four gates -> lane-local LSTM
__global__ void __launch_bounds__(128) k_gates(const bf16* __restrict__ A_in,
                     const bf16* __restrict__ Wcomb, const float* __restrict__ bsum,
                     float* __restrict__ c_f32, bf16* __restrict__ A_out,
                     bf16* __restrict__ q_buf)
{
    int m0 = blockIdx.x * 32 + (threadIdx.x >> 6) * 16;
    int j0 = blockIdx.y * 16;
    int lane = threadIdx.x & 63;
    int r  = lane & 15;
    int ko = (lane >> 4) * 8;
    const short* ap = (const short*)A_in;
    const short* wp = (const short*)Wcomb;
    f32x4 acc[4] = {};
    long arow = (long)(m0 + r) * KG;
    for (int k0 = 0; k0 < KG; k0 += 32) {
        bf16x8 a = *(const bf16x8*)(ap + arow + k0 + ko);
        #pragma unroll
        for (int g = 0; g < 4; ++g) {
            bf16x8 bb = *(const bf16x8*)(wp + (long)(g*512 + j0 + r) * KG + k0 + ko);
            acc[g] = __builtin_amdgcn_mfma_f32_16x16x32_bf16(a, bb, acc[g], 0, 0, 0);
        }
    }
    int jj = j0 + r;
    float bi  = bsum[jj];
    float bff = bsum[512 + jj];
    float bg  = bsum[1024 + jj];
    float bo  = bsum[1536 + jj];
    #pragma unroll
    for (int j = 0; j < 4; ++j) {
        int b = m0 + (lane >> 4) * 4 + j;
        float iv = acc[0][j] + bi;
        float fv = acc[1][j] + bff;
        float gv = acc[2][j] + bg;
        float ov = acc[3][j] + bo;
        float c_old = c_f32[(long)b * H_ + jj];
        float cn = fast_sig(fv) * c_old + fast_sig(iv) * fast_tanh(gv);
        float hn = fast_sig(ov) * fast_tanh(cn);
        c_f32[(long)b * H_ + jj] = cn;
        bf16 hb = __float2bfloat16(hn);
        A_out[(long)b * KG + 320 + jj]  = hb;
        q_buf[(long)b * K2H + jj]       = hb;
        q_buf[(long)b * K2H + 512 + jj] = __float2bfloat16(cn);
    }
}

// ---------------------------------------------------------------------------
extern "C" void kernel_launch(void* const* d_in, const int* in_sizes, int n_in,
                              void* d_out, int out_size, void* d_ws, size_t ws_size,
                              hipStream_t stream)
{
    const float* x    = (const float*)d_in[0];
    const float* V    = (const float*)d_in[1];
    const float* W    = (const float*)d_in[2];
    const float* U    = (const float*)d_in[3];
    const float* W_ih = (const float*)d_in[4];
    const float* W_hh = (const float*)d_in[5];
    const float* b_ih = (const float*)d_in[6];
    const float* b_hh = (const float*)d_in[7];
    const float* Wd   = (const float*)d_in[8];
    const float* bd   = (const float*)d_in[9];
    const float* Ws   = (const float*)d_in[10];
    const float* bs   = (const float*)d_in[11];
    const float* Wc   = (const float*)d_in[12];
    const float* bc   = (const float*)d_in[13];

    float* out_y = (float*)d_out;                         // (512,64,64)
    float* out_w = (float*)d_out + (long)B_ * P_ * O_;    // (512,64,128)

    // workspace carve-up (aligned to 256B)
    char* p = (char*)d_ws;
    auto alloc = [&](size_t bytes) { char* r = p; p += (bytes + 255) & ~(size_t)255; return r; };
    bf16*  x_bf  = (bf16*) alloc((size_t)B_ * WIN_ * D_ * 2);   // 33.5 MB
    bf16*  Uk    = (bf16*) alloc((size_t)B_ * D_ * WIN_ * 2);   // 33.5 MB
    bf16*  q_buf = (bf16*) alloc((size_t)B_ * K2H * 2);         // 1 MB
    bf16*  A0    = (bf16*) alloc((size_t)B_ * KG * 2);          // 852 KB
    bf16*  A1    = (bf16*) alloc((size_t)B_ * KG * 2);          // 852 KB
    float* Wq    = (float*)alloc((size_t)B_ * D_ * 4);          // 512 KB
    float* c_f32 = (float*)alloc((size_t)B_ * H_ * 4);          // 1 MB
    bf16*  Wqy   = (bf16*) alloc((size_t)NQY * K2H * 2);        // 640 KB
    bf16*  Wcomb = (bf16*) alloc((size_t)2048 * KG * 2);        // 3.3 MB
    bf16*  U_bf  = (bf16*) alloc((size_t)D_ * D_ * 2);          // 128 KB
    float* bsum  = (float*)alloc((size_t)2048 * 4);             // 8 KB
    bf16*  Abuf[2] = { A0, A1 };

    // prep
    k_prep<<<8192, 256, 0, stream>>>(x, W, U, W_ih, W_hh, b_ih, b_hh, Wd,
                                     x_bf, Wcomb, Wqy, U_bf, bsum, A0);
    k_init<<<1024, 256, 0, stream>>>(x, Ws, bs, Wc, bc, q_buf, A0, c_f32);
    k_uk<<<dim3(B_, 8), 256, 0, stream>>>(U_bf, x_bf, Uk);

    // decode loop
    for (int s = 0; s < P_; ++s) {
        k_wqy<<<dim3(32, 10), 64, 0, stream>>>(q_buf, Wqy, bd, Wq, out_y,
                                               Abuf[s & 1], s - 1);
        k_att<<<B_, 256, 0, stream>>>(Wq, V, Uk, x_bf, out_w, Abuf[s & 1], s);
        k_gates<<<dim3(16, 32), 128, 0, stream>>>(Abuf[s & 1], Wcomb, bsum,
                                                  c_f32, Abuf[(s + 1) & 1], q_buf);
    }
    // final y_63 = h_64 @ Wd^T + bd
    k_wqy<<<dim3(32, 10), 64, 0, stream>>>(q_buf, Wqy, bd, Wq, out_y, Abuf[0], 63);
}